// Round 11
// baseline (21402.943 us; speedup 1.0000x reference)
//
#include <hip/hip_runtime.h>

#define BB 256
#define SS 336
#define HH 512
#define NT 431   // output time steps
#define NU 432   // total cell steps (336 enc + 96 pred)

typedef __attribute__((ext_vector_type(8))) short bf16x8;
typedef __attribute__((ext_vector_type(16))) float f32x16;
typedef __attribute__((ext_vector_type(4))) int i32x4;   // native vector: ok for asm "v"

// ---------------- ws layout (bytes) ----------------
// wFrag : 4 matrices (lin_whh, lin_wih, quat_whh, quat_wih), fragment-order bf16
//         each 2048*512*2B = 2 MB                              @ 0
//         order per mat: [cg(16)][wq(4)][kb(32)][lane(64)][8]
// hbuf  : 2 parity * 2 branch * 8rg*32kb*64lane*8 bf16 (1 MB)  @ 8388608
// bar   : 64 blocks * 64 B = 4 KB (16 KB reserved)             @ 9437184
// M     : [2][2048][4] f32                                     @ 10485760
// bE    : [2][2048] f32                                        @ 10551296
// bP    : [2][2048] f32                                        @ 10567680

__device__ inline unsigned short f2bf(float f) {
    unsigned int u = __float_as_uint(f);
    unsigned int r = (u + 0x7fffu + ((u >> 16) & 1u)) >> 16;
    return (unsigned short)r;
}
__device__ inline float sigm(float x) { return 1.f / (1.f + __expf(-x)); }
__device__ inline float tanh_(float x) { return 2.f / (1.f + __expf(-2.f * x)) - 1.f; }

// LLC-coherent (cross-XCD) 16B load/store: sc0 sc1 bypass L1/L2.
__device__ inline i32x4 llc_load_b128(const i32x4* p) {
    i32x4 r;
    asm volatile("global_load_dwordx4 %0, %1, off sc0 sc1" : "=v"(r) : "v"(p));
    return r;   // NOT ready until vm_drain()!
}
__device__ inline void llc_store_b128(i32x4* p, i32x4 v) {
    asm volatile("global_store_dwordx4 %0, %1, off sc0 sc1" :: "v"(p), "v"(v) : "memory");
}
__device__ inline void vm_drain() { asm volatile("s_waitcnt vmcnt(0)" ::: "memory"); }

// Convert the 4 recurrent weight matrices [2048][512] f32 -> bf16 in MFMA
// B-fragment order: [mat][cg(16)][wq(4)][kb(32)][lane(64)][8]
__global__ void k_wfrag(const float* __restrict__ w0, const float* __restrict__ w1,
                        const float* __restrict__ w2, const float* __restrict__ w3,
                        unsigned short* __restrict__ wfrag) {
    int idx = blockIdx.x * 256 + threadIdx.x;      // 0 .. 524287
    int mat = idx >> 17;
    int t = idx & 131071;
    int lane = t & 63;
    int kb = (t >> 6) & 31;
    int wq = (t >> 11) & 3;
    int cg = t >> 13;                               // 0..15
    const float* W = mat == 0 ? w0 : (mat == 1 ? w1 : (mat == 2 ? w2 : w3));
    int n = wq * 512 + cg * 32 + (lane & 31);       // global gate row
    int k0 = kb * 16 + (lane >> 5) * 8;
    const float* src = W + n * 512 + k0;
    unsigned short us[8];
#pragma unroll
    for (int j = 0; j < 8; ++j) us[j] = f2bf(src[j]);
    i32x4 v;
    v.x = us[0] | (us[1] << 16); v.y = us[2] | (us[3] << 16);
    v.z = us[4] | (us[5] << 16); v.w = us[6] | (us[7] << 16);
    ((i32x4*)wfrag)[idx] = v;
}

// M = Wih@We  [2][2048][4], bE = Wih@be + bih + bhh, bP = bih + bhh
__global__ void k_mbias(const float* __restrict__ lin_wih, const float* __restrict__ quat_wih,
                        const float* __restrict__ lin_enc_w, const float* __restrict__ quat_enc_w,
                        const float* __restrict__ lin_enc_b, const float* __restrict__ quat_enc_b,
                        const float* __restrict__ lin_bih, const float* __restrict__ lin_bhh,
                        const float* __restrict__ quat_bih, const float* __restrict__ quat_bhh,
                        float* __restrict__ M, float* __restrict__ bE, float* __restrict__ bP) {
    int gid = blockIdx.x * 256 + threadIdx.x;      // 0..4095
    int branch = gid >> 11;
    int n = gid & 2047;
    int nf = 3 + branch;
    const float* Wih = branch ? quat_wih : lin_wih;
    const float* We  = branch ? quat_enc_w : lin_enc_w;
    const float* be  = branch ? quat_enc_b : lin_enc_b;
    const float* bih = branch ? quat_bih : lin_bih;
    const float* bhh = branch ? quat_bhh : lin_bhh;
    float m[4] = {0.f, 0.f, 0.f, 0.f};
    float bs = 0.f;
    for (int j = 0; j < 512; ++j) {
        float w = Wih[n * 512 + j];
#pragma unroll
        for (int kf = 0; kf < 4; ++kf)
            if (kf < nf) m[kf] += w * We[j * nf + kf];
        bs += w * be[j];
    }
    float* Mp = M + (branch * 2048 + n) * 4;
#pragma unroll
    for (int kf = 0; kf < 4; ++kf) Mp[kf] = m[kf];
    bE[branch * 2048 + n] = bs + bih[n] + bhh[n];
    bP[branch * 2048 + n] = bih[n] + bhh[n];
}

__global__ void k_zero(i32x4* __restrict__ p) {
    int idx = blockIdx.x * 256 + threadIdx.x;      // 260 blocks: hbuf (1 MB) + bar (16 KB)
    p[idx] = i32x4{0, 0, 0, 0};
}

// Persistent kernel: all 432 LSTM steps for both branches.
// 64 blocks x 1024 threads (16 waves, 1 block/CU via ~125 KB LDS).
// blk = branch*32 + rg*4 + cq: branch, rg = 32-row group, cq = 512-gatecol group.
// Wave wv (0..15): gate = wv>>2, col-block cgl = wv&3 -> 32 gatecols, bw[32] B-frags
// (identical per-wave structure to the verified 256-thread version).
// Groups of FOUR blocks (share (branch,rg) row slice) — 4 flags to poll, 4-peer
// skew, and the 32 KB A-tile staged once per 16 waves. Groups are by blockIdx
// => placement-independent (partial residency serializes, cannot deadlock).
// h via sc0/sc1 LLC ops; per-block step flags; watchdog converts any protocol
// flaw into a numeric failure instead of a wedge.
__global__ __launch_bounds__(1024, 1) void k_persist(
    const float* __restrict__ x,
    const unsigned short* __restrict__ wfrag,
    const float* __restrict__ M, const float* __restrict__ bE, const float* __restrict__ bP,
    const float* __restrict__ lin_dec_w, const float* __restrict__ quat_dec_w,
    const float* __restrict__ lin_dec_b, const float* __restrict__ quat_dec_b,
    unsigned short* __restrict__ hbuf,
    float* __restrict__ out,
    unsigned int* __restrict__ bar) {
    __shared__ i32x4 lds_a[2048];      // staged A tile: [kb(32)][lane(64)] = 32 KB
    __shared__ float g_lds[32 * 517];  // 32 rows x 512 gatecols, stride 517 (bank-clean)
    __shared__ float h_tile[32 * 129]; // 32 rows x 128 h-cols (+1 pad)
    __shared__ float mE[2048];         // [gate(4)][jj(128)][kf(4)]
    __shared__ float bEs[512];         // [gate(4)][jj(128)]
    __shared__ float bPs[512];

    const int tid = threadIdx.x;
    const int lane = tid & 63;
    const int wv = tid >> 6;           // 0..15
    const int gate = wv >> 2;          // GEMM: wave's gate
    const int cgl = wv & 3;            // GEMM: wave's 32-col block within the 128 h-cols
    const int blk = blockIdx.x;
    const int branch = blk >> 5;
    const int rg = (blk >> 2) & 7;     // 32-row group
    const int cq = blk & 3;            // 128-h-col group (512 gatecols)
    const int group = blk >> 2;        // 0..15
    const int nf = 3 + branch;
    const int row = tid & 31;
    const int jbase = (tid >> 5) & 31; // 0..31 (jj = jbase*4+p covers 0..127)
    const int b = rg * 32 + row;

    // ---- one-time LDS staging of per-block constants
    for (int t = tid; t < 2048; t += 1024) {
        int g = t >> 9, jj = (t >> 2) & 127, kf = t & 3;
        mE[t] = M[(size_t)(branch * 2048 + g * 512 + cq * 128 + jj) * 4 + kf];
    }
    if (tid < 512) {
        int g = tid >> 7, jj = tid & 127;
        bEs[tid] = bE[branch * 2048 + g * 512 + cq * 128 + jj];
        bPs[tid] = bP[branch * 2048 + g * 512 + cq * 128 + jj];
    }

    // ---- decoder role (waves 12..15): 2 rows per wave, 8 rows per block
    const int w4   = wv - 12;                   // 0..3 when decoding
    const int dr   = lane & 1;
    const int dd   = (lane >> 1) & 3;           // decoder output dim
    const int dseg = lane >> 3;                 // 0..7, 64-wide k segment
    const int drow = cq * 8 + w4 * 2 + dr;      // row within the 32-row slice
    const bool dvalid = dd < nf;
    const float* dwp = (branch ? quat_dec_w : lin_dec_w) + dd * 512;
    const float dbias = dvalid ? (branch ? quat_dec_b : lin_dec_b)[dd] : 0.f;

    // ---- register-resident weight fragments (enc matrix first)
    const i32x4* BpE = (const i32x4*)wfrag + (size_t)(branch * 2) * 131072
                       + (size_t)(((cq * 4 + cgl) * 4 + gate) * 32) * 64 + lane;
    const i32x4* BpP = BpE + 131072;
    i32x4 bw[32];
#pragma unroll
    for (int kb = 0; kb < 32; ++kb) bw[kb] = BpE[kb * 64];

    float creg[4] = {0.f, 0.f, 0.f, 0.f};

    __syncthreads();

    for (int u = 0; u <= NU; ++u) {
        const int is_enc = (u < SS);

        // x loads: read-only, L1-cached
        float xv0 = 0.f, xv1 = 0.f, xv2 = 0.f, xv3 = 0.f;
        if (is_enc) {
            const float* xp = x + ((size_t)b * SS + u) * 7 + branch * 3;
            xv0 = xp[0]; xv1 = xp[1]; xv2 = xp[2];
            if (branch) xv3 = xp[3];
        }
        if (u == SS) {      // enc -> pred weight switch (Whh -> Wih)
#pragma unroll
            for (int kb = 0; kb < 32; ++kb) bw[kb] = BpP[kb * 64];
        }

        // ---- group barrier: wave 0, 4 lanes poll the 4 peer flags (LLC)
        if (u > 0) {
            if (wv == 0) {
                const unsigned int* slot = bar + (size_t)((group << 2) | (lane & 3)) * 16;
                int guard = 0;
                for (;;) {
                    unsigned int v = 0xFFFFFFFFu;
                    if (lane < 4)
                        asm volatile("global_load_dword %0, %1, off sc0 sc1\n\ts_waitcnt vmcnt(0)"
                                     : "=v"(v) : "v"(slot) : "memory");
                    if (__all((int)(v >= (unsigned int)u))) break;
                    if (++guard > (1 << 18)) break;   // watchdog (never fires when healthy)
                    __builtin_amdgcn_s_sleep(1);
                }
            }
            __syncthreads();
        }

        // ---- stage A tile (32 rows x 512 h, bf16 fragments) LLC -> LDS (2/thread)
        {
            const i32x4* gsrc = (const i32x4*)hbuf + (size_t)(u & 1) * 32768
                                + (size_t)branch * 16384 + rg * 2048 + tid;
            i32x4 av0 = llc_load_b128(gsrc);
            i32x4 av1 = llc_load_b128(gsrc + 1024);
            vm_drain();
            __builtin_amdgcn_sched_barrier(0);
            lds_a[tid] = av0;
            lds_a[1024 + tid] = av1;
        }
        __syncthreads();

        if (u == NU) {      // final iteration: only decode h_{NU-1} -> t = NU-2
            if (wv >= 12) {
                float s = 0.f;
                if (dvalid) {
                    const unsigned short* hp = (const unsigned short*)lds_a;
#pragma unroll
                    for (int jj = 0; jj < 64; ++jj) {
                        int j = dseg * 64 + jj;
                        unsigned short hu = hp[(j >> 4) * 512 + ((j >> 3) & 1) * 256 + drow * 8 + (j & 7)];
                        s += __uint_as_float(((unsigned int)hu) << 16) * dwp[j];
                    }
                }
                s += __shfl_xor(s, 8);
                s += __shfl_xor(s, 16);
                s += __shfl_xor(s, 32);
                if (dseg == 0 && dvalid)
                    out[((size_t)(rg * 32 + drow) * NT + (u - 2)) * 7 + branch * 3 + dd] = s + dbias;
            }
            break;
        }

        // ---- GEMM: g[32 x 512] = h[32 x 512] @ W_sliceT; A from LDS (16-wave shared)
        f32x16 acc = {};
        const i32x4* Afrag = lds_a + lane;
#pragma unroll
        for (int kb = 0; kb < 32; ++kb) {
            i32x4 a0 = Afrag[kb * 64];
            acc = __builtin_amdgcn_mfma_f32_32x32x16_bf16(*(const bf16x8*)&a0, *(const bf16x8*)&bw[kb], acc, 0, 0, 0);
        }
        // C layout (32x32): col = lane&31, row = (reg&3) + 8*(reg>>2) + 4*(lane>>5)
        {
            int col_l = gate * 128 + cgl * 32 + (lane & 31);
            int rbase = 4 * (lane >> 5);
#pragma unroll
            for (int r = 0; r < 16; ++r) {
                int row_l = rbase + (r & 3) + 8 * (r >> 2);
                g_lds[row_l * 517 + col_l] = acc[r];
            }
        }
        __syncthreads();

        // ---- gates: thread handles row = tid&31, jj = jbase*4 + p (0..127)
#pragma unroll
        for (int p = 0; p < 4; ++p) {
            int jj = jbase * 4 + p;
            float gi = g_lds[row * 517 + jj];
            float gf = g_lds[row * 517 + 128 + jj];
            float gc = g_lds[row * 517 + 256 + jj];
            float go = g_lds[row * 517 + 384 + jj];
            if (is_enc) {
                int j4 = jj * 4;
                gi += bEs[jj]       + xv0 * mE[j4]        + xv1 * mE[j4 + 1]        + xv2 * mE[j4 + 2]        + xv3 * mE[j4 + 3];
                gf += bEs[128 + jj] + xv0 * mE[512 + j4]  + xv1 * mE[512 + j4 + 1]  + xv2 * mE[512 + j4 + 2]  + xv3 * mE[512 + j4 + 3];
                gc += bEs[256 + jj] + xv0 * mE[1024 + j4] + xv1 * mE[1024 + j4 + 1] + xv2 * mE[1024 + j4 + 2] + xv3 * mE[1024 + j4 + 3];
                go += bEs[384 + jj] + xv0 * mE[1536 + j4] + xv1 * mE[1536 + j4 + 1] + xv2 * mE[1536 + j4 + 2] + xv3 * mE[1536 + j4 + 3];
            } else {
                gi += bPs[jj];
                gf += bPs[128 + jj];
                gc += bPs[256 + jj];
                go += bPs[384 + jj];
            }
            float iv = sigm(gi), fv = sigm(gf), gv = tanh_(gc), ov = sigm(go);
            float cn;
            if (is_enc) {
                cn = fv * creg[p] + iv * gv;
                creg[p] = cn;
            } else {
                cn = iv * gv;   // pred steps start from zero state
            }
            h_tile[row * 129 + jj] = ov * tanh_(cn);
        }
        __syncthreads();

        // ---- pack h_new (bf16, fragment order) -> LLC: waves 0..3, 2 chunks each
        if (wv < 4) {
#pragma unroll
            for (int c = 0; c < 2; ++c) {
                int c2 = wv * 2 + c;                      // 0..7: 16-col chunk
                int jjb = c2 * 16 + (lane >> 5) * 8;      // local h-col base
                unsigned short us[8];
#pragma unroll
                for (int j = 0; j < 8; ++j) us[j] = f2bf(h_tile[(lane & 31) * 129 + jjb + j]);
                i32x4 v;
                v.x = us[0] | (us[1] << 16); v.y = us[2] | (us[3] << 16);
                v.z = us[4] | (us[5] << 16); v.w = us[6] | (us[7] << 16);
                int kb = cq * 8 + c2;                     // global kb-block
                llc_store_b128((i32x4*)hbuf + (size_t)((u + 1) & 1) * 32768
                               + (size_t)branch * 16384 + rg * 2048 + kb * 64 + lane, v);
            }
            vm_drain();      // h-stores ACKed at LLC before the flag can be written
        }
        __syncthreads();

        // ---- arrive: publish step completion
        if (tid == 0) {
            unsigned int fl = (unsigned int)(u + 1);
            unsigned int* myslot = bar + (size_t)blk * 16;
            asm volatile("global_store_dword %0, %1, off sc0 sc1" :: "v"(myslot), "v"(fl) : "memory");
        }

        // ---- decode h_{u-1} (waves 12..15, off the critical path, after arrive)
        if (wv >= 12 && u >= 2) {
            float s = 0.f;
            if (dvalid) {
                const unsigned short* hp = (const unsigned short*)lds_a;
#pragma unroll
                for (int jj = 0; jj < 64; ++jj) {
                    int j = dseg * 64 + jj;
                    unsigned short hu = hp[(j >> 4) * 512 + ((j >> 3) & 1) * 256 + drow * 8 + (j & 7)];
                    s += __uint_as_float(((unsigned int)hu) << 16) * dwp[j];
                }
            }
            s += __shfl_xor(s, 8);
            s += __shfl_xor(s, 16);
            s += __shfl_xor(s, 32);
            if (dseg == 0 && dvalid)
                out[((size_t)(rg * 32 + drow) * NT + (u - 2)) * 7 + branch * 3 + dd] = s + dbias;
        }
    }
}

extern "C" void kernel_launch(void* const* d_in, const int* in_sizes, int n_in,
                              void* d_out, int out_size, void* d_ws, size_t ws_size,
                              hipStream_t stream) {
    const float* x          = (const float*)d_in[0];
    const float* lin_enc_w  = (const float*)d_in[1];
    const float* lin_enc_b  = (const float*)d_in[2];
    const float* quat_enc_w = (const float*)d_in[3];
    const float* quat_enc_b = (const float*)d_in[4];
    const float* lin_wih    = (const float*)d_in[5];
    const float* lin_whh    = (const float*)d_in[6];
    const float* lin_bih    = (const float*)d_in[7];
    const float* lin_bhh    = (const float*)d_in[8];
    const float* quat_wih   = (const float*)d_in[9];
    const float* quat_whh   = (const float*)d_in[10];
    const float* quat_bih   = (const float*)d_in[11];
    const float* quat_bhh   = (const float*)d_in[12];
    const float* lin_dec_w  = (const float*)d_in[13];
    const float* lin_dec_b  = (const float*)d_in[14];
    const float* quat_dec_w = (const float*)d_in[15];
    const float* quat_dec_b = (const float*)d_in[16];
    float* out = (float*)d_out;
    char* ws = (char*)d_ws;

    unsigned short* wfrag = (unsigned short*)(ws + 0);
    unsigned short* hbuf  = (unsigned short*)(ws + 8388608ull);
    unsigned int*   bar   = (unsigned int*)(ws + 9437184ull);
    float* M    = (float*)(ws + 10485760ull);
    float* bE   = (float*)(ws + 10551296ull);
    float* bP   = (float*)(ws + 10567680ull);

    k_wfrag<<<2048, 256, 0, stream>>>(lin_whh, lin_wih, quat_whh, quat_wih, wfrag);
    k_mbias<<<16, 256, 0, stream>>>(lin_wih, quat_wih, lin_enc_w, quat_enc_w,
                                    lin_enc_b, quat_enc_b, lin_bih, lin_bhh,
                                    quat_bih, quat_bhh, M, bE, bP);
    k_zero<<<260, 256, 0, stream>>>((i32x4*)(ws + 8388608ull));   // hbuf + bar (flags)

    k_persist<<<64, 1024, 0, stream>>>(x, wfrag, M, bE, bP, lin_dec_w, quat_dec_w,
                                       lin_dec_b, quat_dec_b, hbuf, out, bar);
}

// Round 12
// 4755.744 us; speedup vs baseline: 4.5004x; 4.5004x over previous
//
#include <hip/hip_runtime.h>

#define BB 256
#define SS 336
#define HH 512
#define NT 431   // output time steps
#define NU 432   // total cell steps (336 enc + 96 pred)

typedef __attribute__((ext_vector_type(8))) short bf16x8;
typedef __attribute__((ext_vector_type(16))) float f32x16;
typedef __attribute__((ext_vector_type(4))) int i32x4;   // native vector: ok for asm "v"

// ---------------- ws layout (bytes) ----------------
// wFrag : 4 matrices (lin_whh, lin_wih, quat_whh, quat_wih), fragment-order bf16
//         each 2048*512*2B = 2 MB                              @ 0
//         order per mat: [cq(8)][wv(8)][kb(32)][lane(64)][8]
// hbuf  : 2 parity * 2 branch * 8rg*32kb*64lane*8 bf16 (1 MB)  @ 8388608
// bar   : 128 blocks * 64 B = 8 KB (16 KB reserved)            @ 9437184
// M     : [2][2048][4] f32                                     @ 10485760
// bE    : [2][2048] f32                                        @ 10551296
// bP    : [2][2048] f32                                        @ 10567680

__device__ inline unsigned short f2bf(float f) {
    unsigned int u = __float_as_uint(f);
    unsigned int r = (u + 0x7fffu + ((u >> 16) & 1u)) >> 16;
    return (unsigned short)r;
}
__device__ inline float sigm(float x) { return 1.f / (1.f + __expf(-x)); }
__device__ inline float tanh_(float x) { return 2.f / (1.f + __expf(-2.f * x)) - 1.f; }

// LLC-coherent (cross-XCD) 16B load/store: sc0 sc1 bypass L1/L2.
__device__ inline i32x4 llc_load_b128(const i32x4* p) {
    i32x4 r;
    asm volatile("global_load_dwordx4 %0, %1, off sc0 sc1" : "=v"(r) : "v"(p));
    return r;   // NOT ready until vm_drain()!
}
__device__ inline void llc_store_b128(i32x4* p, i32x4 v) {
    asm volatile("global_store_dwordx4 %0, %1, off sc0 sc1" :: "v"(p), "v"(v) : "memory");
}
__device__ inline void vm_drain() { asm volatile("s_waitcnt vmcnt(0)" ::: "memory"); }

// Convert the 4 recurrent weight matrices [2048][512] f32 -> bf16 in MFMA
// B-fragment order: [mat][cq(8)][wv(8)][kb(32)][lane(64)][8]
// wave wv: gate = wv>>1, hh = wv&1; cols n = gate*512 + cq*64 + hh*32 + (lane&31).
__global__ void k_wfrag(const float* __restrict__ w0, const float* __restrict__ w1,
                        const float* __restrict__ w2, const float* __restrict__ w3,
                        unsigned short* __restrict__ wfrag) {
    int idx = blockIdx.x * 256 + threadIdx.x;      // 0 .. 524287
    int mat = idx >> 17;
    int t = idx & 131071;
    int lane = t & 63;
    int kb = (t >> 6) & 31;
    int wv8 = (t >> 11) & 7;
    int cq = t >> 14;                               // 0..7
    const float* W = mat == 0 ? w0 : (mat == 1 ? w1 : (mat == 2 ? w2 : w3));
    int gate = wv8 >> 1, hh = wv8 & 1;
    int n = gate * 512 + cq * 64 + hh * 32 + (lane & 31);   // global gate row
    int k0 = kb * 16 + (lane >> 5) * 8;
    const float* src = W + n * 512 + k0;
    unsigned short us[8];
#pragma unroll
    for (int j = 0; j < 8; ++j) us[j] = f2bf(src[j]);
    i32x4 v;
    v.x = us[0] | (us[1] << 16); v.y = us[2] | (us[3] << 16);
    v.z = us[4] | (us[5] << 16); v.w = us[6] | (us[7] << 16);
    ((i32x4*)wfrag)[idx] = v;
}

// M = Wih@We  [2][2048][4], bE = Wih@be + bih + bhh, bP = bih + bhh
__global__ void k_mbias(const float* __restrict__ lin_wih, const float* __restrict__ quat_wih,
                        const float* __restrict__ lin_enc_w, const float* __restrict__ quat_enc_w,
                        const float* __restrict__ lin_enc_b, const float* __restrict__ quat_enc_b,
                        const float* __restrict__ lin_bih, const float* __restrict__ lin_bhh,
                        const float* __restrict__ quat_bih, const float* __restrict__ quat_bhh,
                        float* __restrict__ M, float* __restrict__ bE, float* __restrict__ bP) {
    int gid = blockIdx.x * 256 + threadIdx.x;      // 0..4095
    int branch = gid >> 11;
    int n = gid & 2047;
    int nf = 3 + branch;
    const float* Wih = branch ? quat_wih : lin_wih;
    const float* We  = branch ? quat_enc_w : lin_enc_w;
    const float* be  = branch ? quat_enc_b : lin_enc_b;
    const float* bih = branch ? quat_bih : lin_bih;
    const float* bhh = branch ? quat_bhh : lin_bhh;
    float m[4] = {0.f, 0.f, 0.f, 0.f};
    float bs = 0.f;
    for (int j = 0; j < 512; ++j) {
        float w = Wih[n * 512 + j];
#pragma unroll
        for (int kf = 0; kf < 4; ++kf)
            if (kf < nf) m[kf] += w * We[j * nf + kf];
        bs += w * be[j];
    }
    float* Mp = M + (branch * 2048 + n) * 4;
#pragma unroll
    for (int kf = 0; kf < 4; ++kf) Mp[kf] = m[kf];
    bE[branch * 2048 + n] = bs + bih[n] + bhh[n];
    bP[branch * 2048 + n] = bih[n] + bhh[n];
}

__global__ void k_zero(i32x4* __restrict__ p) {
    int idx = blockIdx.x * 256 + threadIdx.x;      // 260 blocks: hbuf (1 MB) + bar (16 KB)
    p[idx] = i32x4{0, 0, 0, 0};
}

// Persistent kernel: all 432 LSTM steps for both branches.
// 128 blocks x 512 threads (8 waves, 2 waves/SIMD => 256-VGPR cap; bw[32]+acc
// ~200 VGPR fits WITHOUT spill — round 11's 16-wave variant spilled at the
// 128-VGPR cap). blk = branch*64 + rg*8 + cq: rg = 32-row group, cq = 64-h-col
// group (256 gatecols). Wave wv: gate = wv>>1, col-half hh = wv&1 — identical
// per-wave structure to the verified rounds 8/10. Groups of EIGHT blocks share
// (branch,rg): 8 flags to poll, 8-peer skew, A-tile staged once per 8 waves.
// Groups by blockIdx => placement-independent (cannot deadlock). h via sc0/sc1
// LLC ops; per-block step flags; watchdog converts any protocol flaw into a
// numeric failure instead of a wedge.
__global__ __launch_bounds__(512, 2) void k_persist(
    const float* __restrict__ x,
    const unsigned short* __restrict__ wfrag,
    const float* __restrict__ M, const float* __restrict__ bE, const float* __restrict__ bP,
    const float* __restrict__ lin_dec_w, const float* __restrict__ quat_dec_w,
    const float* __restrict__ lin_dec_b, const float* __restrict__ quat_dec_b,
    unsigned short* __restrict__ hbuf,
    float* __restrict__ out,
    unsigned int* __restrict__ bar) {
    __shared__ i32x4 lds_a[2048];      // staged A tile: [kb(32)][lane(64)] = 32 KB
    __shared__ float g_lds[32 * 261];  // 32 rows x 256 gatecols, stride 261 (bank-clean)
    __shared__ float h_tile[32 * 65];  // 32 rows x 64 h-cols (+1 pad)
    __shared__ float mE[1024];         // [gate(4)][jj(64)][kf(4)]
    __shared__ float bEs[256];         // [gate(4)][jj(64)]
    __shared__ float bPs[256];

    const int tid = threadIdx.x;
    const int lane = tid & 63;
    const int wv = tid >> 6;           // 0..7
    const int gate = wv >> 1;          // GEMM: wave's gate
    const int hh = wv & 1;             // GEMM: wave's 32-col half of the 64 h-cols
    const int blk = blockIdx.x;
    const int branch = blk >> 6;
    const int rg = (blk >> 3) & 7;     // 32-row group
    const int cq = blk & 7;            // 64-h-col group (256 gatecols)
    const int group = blk >> 3;        // 0..15
    const int nf = 3 + branch;
    const int row = tid & 31;
    const int jbase = tid >> 5;        // 0..15 (jj = jbase*4+p covers 0..63)
    const int b = rg * 32 + row;

    // ---- one-time LDS staging of per-block constants
    for (int t = tid; t < 1024; t += 512) {
        int g = t >> 8, jj = (t >> 2) & 63, kf = t & 3;
        mE[t] = M[(size_t)(branch * 2048 + g * 512 + cq * 64 + jj) * 4 + kf];
    }
    if (tid < 256) {
        int g = tid >> 6, jj = tid & 63;
        bEs[tid] = bE[branch * 2048 + g * 512 + cq * 64 + jj];
        bPs[tid] = bP[branch * 2048 + g * 512 + cq * 64 + jj];
    }

    // ---- decoder role (waves 4..5): 2 rows per wave, 4 rows per block
    const int w2   = wv - 4;                    // 0..1 when decoding
    const int dr   = lane & 1;
    const int dd   = (lane >> 1) & 3;           // decoder output dim
    const int dseg = lane >> 3;                 // 0..7, 64-wide k segment
    const int drow = cq * 4 + w2 * 2 + dr;      // row within the 32-row slice
    const bool dvalid = dd < nf;
    const float* dwp = (branch ? quat_dec_w : lin_dec_w) + dd * 512;
    const float dbias = dvalid ? (branch ? quat_dec_b : lin_dec_b)[dd] : 0.f;

    // ---- register-resident weight fragments (enc matrix first)
    const i32x4* BpE = (const i32x4*)wfrag + (size_t)(branch * 2) * 131072
                       + (size_t)((cq * 8 + wv) * 32) * 64 + lane;
    const i32x4* BpP = BpE + 131072;
    i32x4 bw[32];
#pragma unroll
    for (int kb = 0; kb < 32; ++kb) bw[kb] = BpE[kb * 64];

    float creg[4] = {0.f, 0.f, 0.f, 0.f};

    __syncthreads();

    for (int u = 0; u <= NU; ++u) {
        const int is_enc = (u < SS);

        // x loads: read-only, L1-cached
        float xv0 = 0.f, xv1 = 0.f, xv2 = 0.f, xv3 = 0.f;
        if (is_enc) {
            const float* xp = x + ((size_t)b * SS + u) * 7 + branch * 3;
            xv0 = xp[0]; xv1 = xp[1]; xv2 = xp[2];
            if (branch) xv3 = xp[3];
        }
        if (u == SS) {      // enc -> pred weight switch (Whh -> Wih)
#pragma unroll
            for (int kb = 0; kb < 32; ++kb) bw[kb] = BpP[kb * 64];
        }

        // ---- group barrier: wave 0, 8 lanes poll the 8 peer flags (LLC)
        if (u > 0) {
            if (wv == 0) {
                const unsigned int* slot = bar + (size_t)((group << 3) | (lane & 7)) * 16;
                int guard = 0;
                for (;;) {
                    unsigned int v = 0xFFFFFFFFu;
                    if (lane < 8)
                        asm volatile("global_load_dword %0, %1, off sc0 sc1\n\ts_waitcnt vmcnt(0)"
                                     : "=v"(v) : "v"(slot) : "memory");
                    if (__all((int)(v >= (unsigned int)u))) break;
                    if (++guard > (1 << 18)) break;   // watchdog (never fires when healthy)
                    __builtin_amdgcn_s_sleep(1);
                }
            }
            __syncthreads();
        }

        // ---- stage A tile (32 rows x 512 h, bf16 fragments) LLC -> LDS (4/thread)
        {
            const i32x4* gsrc = (const i32x4*)hbuf + (size_t)(u & 1) * 32768
                                + (size_t)branch * 16384 + rg * 2048 + tid;
            i32x4 av0 = llc_load_b128(gsrc);
            i32x4 av1 = llc_load_b128(gsrc + 512);
            i32x4 av2 = llc_load_b128(gsrc + 1024);
            i32x4 av3 = llc_load_b128(gsrc + 1536);
            vm_drain();
            __builtin_amdgcn_sched_barrier(0);
            lds_a[tid] = av0;
            lds_a[512 + tid] = av1;
            lds_a[1024 + tid] = av2;
            lds_a[1536 + tid] = av3;
        }
        __syncthreads();

        if (u == NU) {      // final iteration: only decode h_{NU-1} -> t = NU-2
            if (wv == 4 || wv == 5) {
                float s = 0.f;
                if (dvalid) {
                    const unsigned short* hp = (const unsigned short*)lds_a;
#pragma unroll
                    for (int jj = 0; jj < 64; ++jj) {
                        int j = dseg * 64 + jj;
                        unsigned short hu = hp[(j >> 4) * 512 + ((j >> 3) & 1) * 256 + drow * 8 + (j & 7)];
                        s += __uint_as_float(((unsigned int)hu) << 16) * dwp[j];
                    }
                }
                s += __shfl_xor(s, 8);
                s += __shfl_xor(s, 16);
                s += __shfl_xor(s, 32);
                if (dseg == 0 && dvalid)
                    out[((size_t)(rg * 32 + drow) * NT + (u - 2)) * 7 + branch * 3 + dd] = s + dbias;
            }
            break;
        }

        // ---- GEMM: g[32 x 256] = h[32 x 512] @ W_sliceT; A from LDS (8-wave shared)
        f32x16 acc = {};
        const i32x4* Afrag = lds_a + lane;
#pragma unroll
        for (int kb = 0; kb < 32; ++kb) {
            i32x4 a0 = Afrag[kb * 64];
            acc = __builtin_amdgcn_mfma_f32_32x32x16_bf16(*(const bf16x8*)&a0, *(const bf16x8*)&bw[kb], acc, 0, 0, 0);
        }
        // C layout (32x32): col = lane&31, row = (reg&3) + 8*(reg>>2) + 4*(lane>>5)
        {
            int col_l = gate * 64 + hh * 32 + (lane & 31);
            int rbase = 4 * (lane >> 5);
#pragma unroll
            for (int r = 0; r < 16; ++r) {
                int row_l = rbase + (r & 3) + 8 * (r >> 2);
                g_lds[row_l * 261 + col_l] = acc[r];
            }
        }
        __syncthreads();

        // ---- gates: thread handles row = tid&31, jj = jbase*4 + p (0..63)
#pragma unroll
        for (int p = 0; p < 4; ++p) {
            int jj = jbase * 4 + p;
            float gi = g_lds[row * 261 + jj];
            float gf = g_lds[row * 261 + 64 + jj];
            float gc = g_lds[row * 261 + 128 + jj];
            float go = g_lds[row * 261 + 192 + jj];
            if (is_enc) {
                int j4 = jj * 4;
                gi += bEs[jj]       + xv0 * mE[j4]       + xv1 * mE[j4 + 1]       + xv2 * mE[j4 + 2]       + xv3 * mE[j4 + 3];
                gf += bEs[64 + jj]  + xv0 * mE[256 + j4] + xv1 * mE[256 + j4 + 1] + xv2 * mE[256 + j4 + 2] + xv3 * mE[256 + j4 + 3];
                gc += bEs[128 + jj] + xv0 * mE[512 + j4] + xv1 * mE[512 + j4 + 1] + xv2 * mE[512 + j4 + 2] + xv3 * mE[512 + j4 + 3];
                go += bEs[192 + jj] + xv0 * mE[768 + j4] + xv1 * mE[768 + j4 + 1] + xv2 * mE[768 + j4 + 2] + xv3 * mE[768 + j4 + 3];
            } else {
                gi += bPs[jj];
                gf += bPs[64 + jj];
                gc += bPs[128 + jj];
                go += bPs[192 + jj];
            }
            float iv = sigm(gi), fv = sigm(gf), gv = tanh_(gc), ov = sigm(go);
            float cn;
            if (is_enc) {
                cn = fv * creg[p] + iv * gv;
                creg[p] = cn;
            } else {
                cn = iv * gv;   // pred steps start from zero state
            }
            h_tile[row * 65 + jj] = ov * tanh_(cn);
        }
        __syncthreads();

        // ---- pack h_new -> LLC: waves 0..3, one 16-col chunk each (1 store/lane);
        //      decode h_{u-1} concurrently on waves 4..5
        if (wv < 4) {
            int jjb = wv * 16 + (lane >> 5) * 8;      // local h-col base
            unsigned short us[8];
#pragma unroll
            for (int j = 0; j < 8; ++j) us[j] = f2bf(h_tile[(lane & 31) * 65 + jjb + j]);
            i32x4 v;
            v.x = us[0] | (us[1] << 16); v.y = us[2] | (us[3] << 16);
            v.z = us[4] | (us[5] << 16); v.w = us[6] | (us[7] << 16);
            int kb = cq * 4 + wv;                     // global 16-col block
            llc_store_b128((i32x4*)hbuf + (size_t)((u + 1) & 1) * 32768
                           + (size_t)branch * 16384 + rg * 2048 + kb * 64 + lane, v);
            vm_drain();      // h-stores ACKed at LLC before the flag can be written
        } else if ((wv == 4 || wv == 5) && u >= 2) {
            float s = 0.f;
            if (dvalid) {
                const unsigned short* hp = (const unsigned short*)lds_a;
#pragma unroll
                for (int jj = 0; jj < 64; ++jj) {
                    int j = dseg * 64 + jj;
                    unsigned short hu = hp[(j >> 4) * 512 + ((j >> 3) & 1) * 256 + drow * 8 + (j & 7)];
                    s += __uint_as_float(((unsigned int)hu) << 16) * dwp[j];
                }
            }
            s += __shfl_xor(s, 8);
            s += __shfl_xor(s, 16);
            s += __shfl_xor(s, 32);
            if (dseg == 0 && dvalid)
                out[((size_t)(rg * 32 + drow) * NT + (u - 2)) * 7 + branch * 3 + dd] = s + dbias;
        }
        __syncthreads();     // all pack waves drained before the flag

        // ---- arrive: publish step completion
        if (tid == 0) {
            unsigned int fl = (unsigned int)(u + 1);
            unsigned int* myslot = bar + (size_t)blk * 16;
            asm volatile("global_store_dword %0, %1, off sc0 sc1" :: "v"(myslot), "v"(fl) : "memory");
        }
    }
}

extern "C" void kernel_launch(void* const* d_in, const int* in_sizes, int n_in,
                              void* d_out, int out_size, void* d_ws, size_t ws_size,
                              hipStream_t stream) {
    const float* x          = (const float*)d_in[0];
    const float* lin_enc_w  = (const float*)d_in[1];
    const float* lin_enc_b  = (const float*)d_in[2];
    const float* quat_enc_w = (const float*)d_in[3];
    const float* quat_enc_b = (const float*)d_in[4];
    const float* lin_wih    = (const float*)d_in[5];
    const float* lin_whh    = (const float*)d_in[6];
    const float* lin_bih    = (const float*)d_in[7];
    const float* lin_bhh    = (const float*)d_in[8];
    const float* quat_wih   = (const float*)d_in[9];
    const float* quat_whh   = (const float*)d_in[10];
    const float* quat_bih   = (const float*)d_in[11];
    const float* quat_bhh   = (const float*)d_in[12];
    const float* lin_dec_w  = (const float*)d_in[13];
    const float* lin_dec_b  = (const float*)d_in[14];
    const float* quat_dec_w = (const float*)d_in[15];
    const float* quat_dec_b = (const float*)d_in[16];
    float* out = (float*)d_out;
    char* ws = (char*)d_ws;

    unsigned short* wfrag = (unsigned short*)(ws + 0);
    unsigned short* hbuf  = (unsigned short*)(ws + 8388608ull);
    unsigned int*   bar   = (unsigned int*)(ws + 9437184ull);
    float* M    = (float*)(ws + 10485760ull);
    float* bE   = (float*)(ws + 10551296ull);
    float* bP   = (float*)(ws + 10567680ull);

    k_wfrag<<<2048, 256, 0, stream>>>(lin_whh, lin_wih, quat_whh, quat_wih, wfrag);
    k_mbias<<<16, 256, 0, stream>>>(lin_wih, quat_wih, lin_enc_w, quat_enc_w,
                                    lin_enc_b, quat_enc_b, lin_bih, lin_bhh,
                                    quat_bih, quat_bhh, M, bE, bP);
    k_zero<<<260, 256, 0, stream>>>((i32x4*)(ws + 8388608ull));   // hbuf + bar (flags)

    k_persist<<<128, 512, 0, stream>>>(x, wfrag, M, bE, bP, lin_dec_w, quat_dec_w,
                                       lin_dec_b, quat_dec_b, hbuf, out, bar);
}

// Round 13
// 4741.481 us; speedup vs baseline: 4.5140x; 1.0030x over previous
//
#include <hip/hip_runtime.h>

#define BB 256
#define SS 336
#define HH 512
#define NT 431   // output time steps
#define NU 432   // total cell steps (336 enc + 96 pred)

typedef __attribute__((ext_vector_type(8))) short bf16x8;
typedef __attribute__((ext_vector_type(16))) float f32x16;
typedef __attribute__((ext_vector_type(4))) int i32x4;   // native vector: ok for asm "v"

// ---------------- ws layout (bytes) ----------------
// wFrag : 4 matrices (lin_whh, lin_wih, quat_whh, quat_wih), fragment-order bf16
//         each 2048*512*2B = 2 MB                              @ 0
//         order per mat: [cq(8)][wv(8)][kb(32)][lane(64)][8]
// hbuf  : 2 parity * 2 branch * 8rg*32kb*64lane*8 bf16 (1 MB)  @ 8388608
// bar   : 128 blocks * 64 B = 8 KB (16 KB reserved)            @ 9437184
// M     : [2][2048][4] f32                                     @ 10485760
// bE    : [2][2048] f32                                        @ 10551296
// bP    : [2][2048] f32                                        @ 10567680

__device__ inline unsigned short f2bf(float f) {
    unsigned int u = __float_as_uint(f);
    unsigned int r = (u + 0x7fffu + ((u >> 16) & 1u)) >> 16;
    return (unsigned short)r;
}
__device__ inline float sigm(float x) { return 1.f / (1.f + __expf(-x)); }
__device__ inline float tanh_(float x) { return 2.f / (1.f + __expf(-2.f * x)) - 1.f; }

// LLC-coherent (cross-XCD) 16B load/store: sc0 sc1 bypass L1/L2.
__device__ inline i32x4 llc_load_b128(const i32x4* p) {
    i32x4 r;
    asm volatile("global_load_dwordx4 %0, %1, off sc0 sc1" : "=v"(r) : "v"(p));
    return r;   // NOT ready until vm_drain()!
}
__device__ inline void llc_store_b128(i32x4* p, i32x4 v) {
    asm volatile("global_store_dwordx4 %0, %1, off sc0 sc1" :: "v"(p), "v"(v) : "memory");
}
__device__ inline void vm_drain() { asm volatile("s_waitcnt vmcnt(0)" ::: "memory"); }

// Convert the 4 recurrent weight matrices [2048][512] f32 -> bf16 in MFMA
// B-fragment order: [mat][cq(8)][wv(8)][kb(32)][lane(64)][8]
// wave wv: gate = wv>>1, hh = wv&1; cols n = gate*512 + cq*64 + hh*32 + (lane&31).
__global__ void k_wfrag(const float* __restrict__ w0, const float* __restrict__ w1,
                        const float* __restrict__ w2, const float* __restrict__ w3,
                        unsigned short* __restrict__ wfrag) {
    int idx = blockIdx.x * 256 + threadIdx.x;      // 0 .. 524287
    int mat = idx >> 17;
    int t = idx & 131071;
    int lane = t & 63;
    int kb = (t >> 6) & 31;
    int wv8 = (t >> 11) & 7;
    int cq = t >> 14;                               // 0..7
    const float* W = mat == 0 ? w0 : (mat == 1 ? w1 : (mat == 2 ? w2 : w3));
    int gate = wv8 >> 1, hh = wv8 & 1;
    int n = gate * 512 + cq * 64 + hh * 32 + (lane & 31);   // global gate row
    int k0 = kb * 16 + (lane >> 5) * 8;
    const float* src = W + n * 512 + k0;
    unsigned short us[8];
#pragma unroll
    for (int j = 0; j < 8; ++j) us[j] = f2bf(src[j]);
    i32x4 v;
    v.x = us[0] | (us[1] << 16); v.y = us[2] | (us[3] << 16);
    v.z = us[4] | (us[5] << 16); v.w = us[6] | (us[7] << 16);
    ((i32x4*)wfrag)[idx] = v;
}

// M = Wih@We  [2][2048][4], bE = Wih@be + bih + bhh, bP = bih + bhh
__global__ void k_mbias(const float* __restrict__ lin_wih, const float* __restrict__ quat_wih,
                        const float* __restrict__ lin_enc_w, const float* __restrict__ quat_enc_w,
                        const float* __restrict__ lin_enc_b, const float* __restrict__ quat_enc_b,
                        const float* __restrict__ lin_bih, const float* __restrict__ lin_bhh,
                        const float* __restrict__ quat_bih, const float* __restrict__ quat_bhh,
                        float* __restrict__ M, float* __restrict__ bE, float* __restrict__ bP) {
    int gid = blockIdx.x * 256 + threadIdx.x;      // 0..4095
    int branch = gid >> 11;
    int n = gid & 2047;
    int nf = 3 + branch;
    const float* Wih = branch ? quat_wih : lin_wih;
    const float* We  = branch ? quat_enc_w : lin_enc_w;
    const float* be  = branch ? quat_enc_b : lin_enc_b;
    const float* bih = branch ? quat_bih : lin_bih;
    const float* bhh = branch ? quat_bhh : lin_bhh;
    float m[4] = {0.f, 0.f, 0.f, 0.f};
    float bs = 0.f;
    for (int j = 0; j < 512; ++j) {
        float w = Wih[n * 512 + j];
#pragma unroll
        for (int kf = 0; kf < 4; ++kf)
            if (kf < nf) m[kf] += w * We[j * nf + kf];
        bs += w * be[j];
    }
    float* Mp = M + (branch * 2048 + n) * 4;
#pragma unroll
    for (int kf = 0; kf < 4; ++kf) Mp[kf] = m[kf];
    bE[branch * 2048 + n] = bs + bih[n] + bhh[n];
    bP[branch * 2048 + n] = bih[n] + bhh[n];
}

__global__ void k_zero(i32x4* __restrict__ p) {
    int idx = blockIdx.x * 256 + threadIdx.x;      // 260 blocks: hbuf (1 MB) + bar (16 KB)
    p[idx] = i32x4{0, 0, 0, 0};
}

// Persistent kernel: all 432 LSTM steps for both branches.
// 128 blocks x 512 threads, __launch_bounds__(512, 1): ONE block/CU => 2
// waves/SIMD => 256-VGPR budget, so bw[32] (128 VGPR) + acc stays register-
// resident WITHOUT spill. (Round 12's (512,2) budgeted 2 blocks/CU => 128-VGPR
// cap => bw spilled to scratch: WRITE_SIZE +205 MB, step 6.4->10.4 µs.)
// blk = branch*64 + rg*8 + cq: rg = 32-row group, cq = 64-h-col group (256
// gatecols). Wave wv: gate = wv>>1, col-half hh = wv&1 — per-wave structure
// identical to verified round 8. Groups of EIGHT blocks share (branch,rg):
// 8 flags to poll, 8-peer skew, A-tile staged once per 8 waves. Groups by
// blockIdx => placement-independent (cannot deadlock). h via sc0/sc1 LLC ops;
// per-block step flags; watchdog converts any protocol flaw into a numeric
// failure instead of a wedge.
__global__ __launch_bounds__(512, 1) void k_persist(
    const float* __restrict__ x,
    const unsigned short* __restrict__ wfrag,
    const float* __restrict__ M, const float* __restrict__ bE, const float* __restrict__ bP,
    const float* __restrict__ lin_dec_w, const float* __restrict__ quat_dec_w,
    const float* __restrict__ lin_dec_b, const float* __restrict__ quat_dec_b,
    unsigned short* __restrict__ hbuf,
    float* __restrict__ out,
    unsigned int* __restrict__ bar) {
    __shared__ i32x4 lds_a[2048];      // staged A tile: [kb(32)][lane(64)] = 32 KB
    __shared__ float g_lds[32 * 261];  // 32 rows x 256 gatecols, stride 261 (bank-clean)
    __shared__ float h_tile[32 * 65];  // 32 rows x 64 h-cols (+1 pad)
    __shared__ float mE[1024];         // [gate(4)][jj(64)][kf(4)]
    __shared__ float bEs[256];         // [gate(4)][jj(64)]
    __shared__ float bPs[256];

    const int tid = threadIdx.x;
    const int lane = tid & 63;
    const int wv = tid >> 6;           // 0..7
    const int gate = wv >> 1;          // GEMM: wave's gate
    const int hh = wv & 1;             // GEMM: wave's 32-col half of the 64 h-cols
    const int blk = blockIdx.x;
    const int branch = blk >> 6;
    const int rg = (blk >> 3) & 7;     // 32-row group
    const int cq = blk & 7;            // 64-h-col group (256 gatecols)
    const int group = blk >> 3;        // 0..15
    const int nf = 3 + branch;
    const int row = tid & 31;
    const int jbase = tid >> 5;        // 0..15 (jj = jbase*4+p covers 0..63)
    const int b = rg * 32 + row;

    // ---- one-time LDS staging of per-block constants
    for (int t = tid; t < 1024; t += 512) {
        int g = t >> 8, jj = (t >> 2) & 63, kf = t & 3;
        mE[t] = M[(size_t)(branch * 2048 + g * 512 + cq * 64 + jj) * 4 + kf];
    }
    if (tid < 256) {
        int g = tid >> 6, jj = tid & 63;
        bEs[tid] = bE[branch * 2048 + g * 512 + cq * 64 + jj];
        bPs[tid] = bP[branch * 2048 + g * 512 + cq * 64 + jj];
    }

    // ---- decoder role (waves 4..5): 2 rows per wave, 4 rows per block
    const int w2   = wv - 4;                    // 0..1 when decoding
    const int dr   = lane & 1;
    const int dd   = (lane >> 1) & 3;           // decoder output dim
    const int dseg = lane >> 3;                 // 0..7, 64-wide k segment
    const int drow = cq * 4 + w2 * 2 + dr;      // row within the 32-row slice
    const bool dvalid = dd < nf;
    const float* dwp = (branch ? quat_dec_w : lin_dec_w) + dd * 512;
    const float dbias = dvalid ? (branch ? quat_dec_b : lin_dec_b)[dd] : 0.f;

    // ---- register-resident weight fragments (enc matrix first)
    const i32x4* BpE = (const i32x4*)wfrag + (size_t)(branch * 2) * 131072
                       + (size_t)((cq * 8 + wv) * 32) * 64 + lane;
    const i32x4* BpP = BpE + 131072;
    i32x4 bw[32];
#pragma unroll
    for (int kb = 0; kb < 32; ++kb) bw[kb] = BpE[kb * 64];

    float creg[4] = {0.f, 0.f, 0.f, 0.f};

    __syncthreads();

    for (int u = 0; u <= NU; ++u) {
        const int is_enc = (u < SS);

        // x loads: read-only, L1-cached
        float xv0 = 0.f, xv1 = 0.f, xv2 = 0.f, xv3 = 0.f;
        if (is_enc) {
            const float* xp = x + ((size_t)b * SS + u) * 7 + branch * 3;
            xv0 = xp[0]; xv1 = xp[1]; xv2 = xp[2];
            if (branch) xv3 = xp[3];
        }
        if (u == SS) {      // enc -> pred weight switch (Whh -> Wih)
#pragma unroll
            for (int kb = 0; kb < 32; ++kb) bw[kb] = BpP[kb * 64];
        }

        // ---- group barrier: wave 0, 8 lanes poll the 8 peer flags (LLC)
        if (u > 0) {
            if (wv == 0) {
                const unsigned int* slot = bar + (size_t)((group << 3) | (lane & 7)) * 16;
                int guard = 0;
                for (;;) {
                    unsigned int v = 0xFFFFFFFFu;
                    if (lane < 8)
                        asm volatile("global_load_dword %0, %1, off sc0 sc1\n\ts_waitcnt vmcnt(0)"
                                     : "=v"(v) : "v"(slot) : "memory");
                    if (__all((int)(v >= (unsigned int)u))) break;
                    if (++guard > (1 << 18)) break;   // watchdog (never fires when healthy)
                    __builtin_amdgcn_s_sleep(1);
                }
            }
            __syncthreads();
        }

        // ---- stage A tile (32 rows x 512 h, bf16 fragments) LLC -> LDS (4/thread)
        {
            const i32x4* gsrc = (const i32x4*)hbuf + (size_t)(u & 1) * 32768
                                + (size_t)branch * 16384 + rg * 2048 + tid;
            i32x4 av0 = llc_load_b128(gsrc);
            i32x4 av1 = llc_load_b128(gsrc + 512);
            i32x4 av2 = llc_load_b128(gsrc + 1024);
            i32x4 av3 = llc_load_b128(gsrc + 1536);
            vm_drain();
            __builtin_amdgcn_sched_barrier(0);
            lds_a[tid] = av0;
            lds_a[512 + tid] = av1;
            lds_a[1024 + tid] = av2;
            lds_a[1536 + tid] = av3;
        }
        __syncthreads();

        if (u == NU) {      // final iteration: only decode h_{NU-1} -> t = NU-2
            if (wv == 4 || wv == 5) {
                float s = 0.f;
                if (dvalid) {
                    const unsigned short* hp = (const unsigned short*)lds_a;
#pragma unroll
                    for (int jj = 0; jj < 64; ++jj) {
                        int j = dseg * 64 + jj;
                        unsigned short hu = hp[(j >> 4) * 512 + ((j >> 3) & 1) * 256 + drow * 8 + (j & 7)];
                        s += __uint_as_float(((unsigned int)hu) << 16) * dwp[j];
                    }
                }
                s += __shfl_xor(s, 8);
                s += __shfl_xor(s, 16);
                s += __shfl_xor(s, 32);
                if (dseg == 0 && dvalid)
                    out[((size_t)(rg * 32 + drow) * NT + (u - 2)) * 7 + branch * 3 + dd] = s + dbias;
            }
            break;
        }

        // ---- GEMM: g[32 x 256] = h[32 x 512] @ W_sliceT; A from LDS (8-wave shared)
        f32x16 acc = {};
        const i32x4* Afrag = lds_a + lane;
#pragma unroll
        for (int kb = 0; kb < 32; ++kb) {
            i32x4 a0 = Afrag[kb * 64];
            acc = __builtin_amdgcn_mfma_f32_32x32x16_bf16(*(const bf16x8*)&a0, *(const bf16x8*)&bw[kb], acc, 0, 0, 0);
        }
        // C layout (32x32): col = lane&31, row = (reg&3) + 8*(reg>>2) + 4*(lane>>5)
        {
            int col_l = gate * 64 + hh * 32 + (lane & 31);
            int rbase = 4 * (lane >> 5);
#pragma unroll
            for (int r = 0; r < 16; ++r) {
                int row_l = rbase + (r & 3) + 8 * (r >> 2);
                g_lds[row_l * 261 + col_l] = acc[r];
            }
        }
        __syncthreads();

        // ---- gates: thread handles row = tid&31, jj = jbase*4 + p (0..63)
#pragma unroll
        for (int p = 0; p < 4; ++p) {
            int jj = jbase * 4 + p;
            float gi = g_lds[row * 261 + jj];
            float gf = g_lds[row * 261 + 64 + jj];
            float gc = g_lds[row * 261 + 128 + jj];
            float go = g_lds[row * 261 + 192 + jj];
            if (is_enc) {
                int j4 = jj * 4;
                gi += bEs[jj]       + xv0 * mE[j4]       + xv1 * mE[j4 + 1]       + xv2 * mE[j4 + 2]       + xv3 * mE[j4 + 3];
                gf += bEs[64 + jj]  + xv0 * mE[256 + j4] + xv1 * mE[256 + j4 + 1] + xv2 * mE[256 + j4 + 2] + xv3 * mE[256 + j4 + 3];
                gc += bEs[128 + jj] + xv0 * mE[512 + j4] + xv1 * mE[512 + j4 + 1] + xv2 * mE[512 + j4 + 2] + xv3 * mE[512 + j4 + 3];
                go += bEs[192 + jj] + xv0 * mE[768 + j4] + xv1 * mE[768 + j4 + 1] + xv2 * mE[768 + j4 + 2] + xv3 * mE[768 + j4 + 3];
            } else {
                gi += bPs[jj];
                gf += bPs[64 + jj];
                gc += bPs[128 + jj];
                go += bPs[192 + jj];
            }
            float iv = sigm(gi), fv = sigm(gf), gv = tanh_(gc), ov = sigm(go);
            float cn;
            if (is_enc) {
                cn = fv * creg[p] + iv * gv;
                creg[p] = cn;
            } else {
                cn = iv * gv;   // pred steps start from zero state
            }
            h_tile[row * 65 + jj] = ov * tanh_(cn);
        }
        __syncthreads();

        // ---- pack h_new -> LLC: waves 0..3, one 16-col chunk each (1 store/lane);
        //      decode h_{u-1} concurrently on waves 4..5
        if (wv < 4) {
            int jjb = wv * 16 + (lane >> 5) * 8;      // local h-col base
            unsigned short us[8];
#pragma unroll
            for (int j = 0; j < 8; ++j) us[j] = f2bf(h_tile[(lane & 31) * 65 + jjb + j]);
            i32x4 v;
            v.x = us[0] | (us[1] << 16); v.y = us[2] | (us[3] << 16);
            v.z = us[4] | (us[5] << 16); v.w = us[6] | (us[7] << 16);
            int kb = cq * 4 + wv;                     // global 16-col block
            llc_store_b128((i32x4*)hbuf + (size_t)((u + 1) & 1) * 32768
                           + (size_t)branch * 16384 + rg * 2048 + kb * 64 + lane, v);
            vm_drain();      // h-stores ACKed at LLC before the flag can be written
        } else if ((wv == 4 || wv == 5) && u >= 2) {
            float s = 0.f;
            if (dvalid) {
                const unsigned short* hp = (const unsigned short*)lds_a;
#pragma unroll
                for (int jj = 0; jj < 64; ++jj) {
                    int j = dseg * 64 + jj;
                    unsigned short hu = hp[(j >> 4) * 512 + ((j >> 3) & 1) * 256 + drow * 8 + (j & 7)];
                    s += __uint_as_float(((unsigned int)hu) << 16) * dwp[j];
                }
            }
            s += __shfl_xor(s, 8);
            s += __shfl_xor(s, 16);
            s += __shfl_xor(s, 32);
            if (dseg == 0 && dvalid)
                out[((size_t)(rg * 32 + drow) * NT + (u - 2)) * 7 + branch * 3 + dd] = s + dbias;
        }
        __syncthreads();     // all pack waves drained before the flag

        // ---- arrive: publish step completion
        if (tid == 0) {
            unsigned int fl = (unsigned int)(u + 1);
            unsigned int* myslot = bar + (size_t)blk * 16;
            asm volatile("global_store_dword %0, %1, off sc0 sc1" :: "v"(myslot), "v"(fl) : "memory");
        }
    }
}

extern "C" void kernel_launch(void* const* d_in, const int* in_sizes, int n_in,
                              void* d_out, int out_size, void* d_ws, size_t ws_size,
                              hipStream_t stream) {
    const float* x          = (const float*)d_in[0];
    const float* lin_enc_w  = (const float*)d_in[1];
    const float* lin_enc_b  = (const float*)d_in[2];
    const float* quat_enc_w = (const float*)d_in[3];
    const float* quat_enc_b = (const float*)d_in[4];
    const float* lin_wih    = (const float*)d_in[5];
    const float* lin_whh    = (const float*)d_in[6];
    const float* lin_bih    = (const float*)d_in[7];
    const float* lin_bhh    = (const float*)d_in[8];
    const float* quat_wih   = (const float*)d_in[9];
    const float* quat_whh   = (const float*)d_in[10];
    const float* quat_bih   = (const float*)d_in[11];
    const float* quat_bhh   = (const float*)d_in[12];
    const float* lin_dec_w  = (const float*)d_in[13];
    const float* lin_dec_b  = (const float*)d_in[14];
    const float* quat_dec_w = (const float*)d_in[15];
    const float* quat_dec_b = (const float*)d_in[16];
    float* out = (float*)d_out;
    char* ws = (char*)d_ws;

    unsigned short* wfrag = (unsigned short*)(ws + 0);
    unsigned short* hbuf  = (unsigned short*)(ws + 8388608ull);
    unsigned int*   bar   = (unsigned int*)(ws + 9437184ull);
    float* M    = (float*)(ws + 10485760ull);
    float* bE   = (float*)(ws + 10551296ull);
    float* bP   = (float*)(ws + 10567680ull);

    k_wfrag<<<2048, 256, 0, stream>>>(lin_whh, lin_wih, quat_whh, quat_wih, wfrag);
    k_mbias<<<16, 256, 0, stream>>>(lin_wih, quat_wih, lin_enc_w, quat_enc_w,
                                    lin_enc_b, quat_enc_b, lin_bih, lin_bhh,
                                    quat_bih, quat_bhh, M, bE, bP);
    k_zero<<<260, 256, 0, stream>>>((i32x4*)(ws + 8388608ull));   // hbuf + bar (flags)

    k_persist<<<128, 512, 0, stream>>>(x, wfrag, M, bE, bP, lin_dec_w, quat_dec_w,
                                       lin_dec_b, quat_dec_b, hbuf, out, bar);
}